// Round 1
// baseline (88.311 us; speedup 1.0000x reference)
//
#include <hip/hip_runtime.h>

// PairwiseRankingLoss: B=128 rows, L=1024 elements/row.
// loss = sum_{b, pos i, neg j} relu(1 - s[b,i] + s[b,j]) / max(num_pairs, 1)
// where num_pairs = sum_b npos_b * nneg_b  (guarded: if 0 pairs, return raw total).

#define PRL_B 128
#define PRL_L 1024

__global__ __launch_bounds__(256) void prl_row_kernel(
    const float* __restrict__ y_pred,
    const int*   __restrict__ y_true,
    float* __restrict__ row_sum,
    int*   __restrict__ row_pos,
    int*   __restrict__ row_neg)
{
    __shared__ float s_score[PRL_L];
    __shared__ int   s_lab[PRL_L];
    __shared__ float s_wsum[4];
    __shared__ int   s_wpos[4];
    __shared__ int   s_wneg[4];

    const int b = blockIdx.x;
    const int t = threadIdx.x;
    const float* pred = y_pred + (size_t)b * PRL_L;
    const int*   lab  = y_true + (size_t)b * PRL_L;

    // Stage row into LDS (coalesced).
    for (int i = t; i < PRL_L; i += 256) {
        s_score[i] = pred[i];
        s_lab[i]   = lab[i];
    }
    __syncthreads();

    // Each thread owns 4 candidate positive positions.
    float p[4];
    int cpos = 0, cneg = 0;
#pragma unroll
    for (int k = 0; k < 4; ++k) {
        const int i  = t + k * 256;
        const int lv = s_lab[i];
        cpos += (lv == 1);
        cneg += (lv == 0);
        // Invalid (non-positive) slot -> huge sentinel so (d - p) is very
        // negative and fmaxf(...,0) contributes 0. Finite to avoid inf-inf.
        p[k] = (lv == 1) ? s_score[i] : 3.0e38f;
    }

    // Inner loop over all j: wave-uniform LDS broadcast reads, uniform branch.
    float acc[4] = {0.f, 0.f, 0.f, 0.f};
    for (int j = 0; j < PRL_L; ++j) {
        if (s_lab[j] == 0) {
            const float d = 1.0f + s_score[j];
#pragma unroll
            for (int k = 0; k < 4; ++k)
                acc[k] += fmaxf(d - p[k], 0.0f);
        }
    }
    float local = (acc[0] + acc[1]) + (acc[2] + acc[3]);

    // Wave (64-lane) shuffle reduction.
#pragma unroll
    for (int off = 32; off >= 1; off >>= 1) {
        local += __shfl_down(local, off, 64);
        cpos  += __shfl_down(cpos,  off, 64);
        cneg  += __shfl_down(cneg,  off, 64);
    }
    const int wave = t >> 6;
    if ((t & 63) == 0) {
        s_wsum[wave] = local;
        s_wpos[wave] = cpos;
        s_wneg[wave] = cneg;
    }
    __syncthreads();
    if (t == 0) {
        float rs = 0.f; int rp = 0, rn = 0;
#pragma unroll
        for (int w = 0; w < 4; ++w) { rs += s_wsum[w]; rp += s_wpos[w]; rn += s_wneg[w]; }
        row_sum[b] = rs;
        row_pos[b] = rp;
        row_neg[b] = rn;
    }
}

__global__ __launch_bounds__(128) void prl_finalize(
    const float* __restrict__ row_sum,
    const int*   __restrict__ row_pos,
    const int*   __restrict__ row_neg,
    float* __restrict__ out)
{
    __shared__ float     s_sum[2];
    __shared__ long long s_pairs[2];
    const int t = threadIdx.x;

    float     s  = row_sum[t];
    long long pr = (long long)row_pos[t] * (long long)row_neg[t];

#pragma unroll
    for (int off = 32; off >= 1; off >>= 1) {
        s  += __shfl_down(s,  off, 64);
        pr += __shfl_down(pr, off, 64);
    }
    const int wave = t >> 6;
    if ((t & 63) == 0) { s_sum[wave] = s; s_pairs[wave] = pr; }
    __syncthreads();
    if (t == 0) {
        const float     total = s_sum[0] + s_sum[1];
        const long long pairs = s_pairs[0] + s_pairs[1];
        const float     npf   = (float)pairs;
        out[0] = (pairs > 0) ? (total / fmaxf(npf, 1.0f)) : total;
    }
}

extern "C" void kernel_launch(void* const* d_in, const int* in_sizes, int n_in,
                              void* d_out, int out_size, void* d_ws, size_t ws_size,
                              hipStream_t stream) {
    const float* y_pred = (const float*)d_in[0];
    const int*   y_true = (const int*)d_in[1];
    float* out = (float*)d_out;

    // Workspace layout: float row_sum[B]; int row_pos[B]; int row_neg[B]
    float* row_sum = (float*)d_ws;
    int*   row_pos = (int*)(row_sum + PRL_B);
    int*   row_neg = row_pos + PRL_B;

    prl_row_kernel<<<PRL_B, 256, 0, stream>>>(y_pred, y_true, row_sum, row_pos, row_neg);
    prl_finalize<<<1, PRL_B, 0, stream>>>(row_sum, row_pos, row_neg, out);
}

// Round 2
// 17.438 us; speedup vs baseline: 5.0643x; 5.0643x over previous
//
#include <hip/hip_runtime.h>

// PairwiseRankingLoss: B=128 rows, L=1024.
// loss = sum_{b, pos i, neg j} relu(1 - s[b,i] + s[b,j]) / max(num_pairs, 1)

#define PRL_B 128
#define PRL_L 1024
#define SPLIT 8
#define JS (PRL_L / SPLIT) // 128 j's per block

// Partial kernel: grid (SPLIT, B). Block (s, b) computes hinge sum over
// (all 1024 candidate-pos i) x (j in slice s), branchless via sentinels:
//   d[j]  = (lab==0) ? 1+score[j] : -3e38   (invalid j -> contributes 0)
//   p[i]  = (lab==1) ? score[i]   : +3e38   (invalid i -> contributes 0)
__global__ __launch_bounds__(256) void prl_partial(
    const float* __restrict__ y_pred,
    const int*   __restrict__ y_true,
    float* __restrict__ partial_sum,   // [B*SPLIT]
    int*   __restrict__ partial_neg,   // [B*SPLIT]
    int*   __restrict__ pos_count)     // [B]
{
    __shared__ float s_d[PRL_L];
    __shared__ float s_wsum[4];
    __shared__ int   s_wpos[4];
    __shared__ int   s_wneg[4];

    const int s = blockIdx.x;
    const int b = blockIdx.y;
    const int t = threadIdx.x;
    const int js = s * JS;

    const float* pred = y_pred + (size_t)b * PRL_L;
    const int*   lab  = y_true + (size_t)b * PRL_L;

    float p[4];
    int cpos = 0, cneg = 0;
#pragma unroll
    for (int k = 0; k < 4; ++k) {
        const int i  = t + k * 256;
        const float sc = pred[i];
        const int   lv = lab[i];
        s_d[i] = (lv == 0) ? (1.0f + sc) : -3.0e38f;
        p[k]   = (lv == 1) ? sc : 3.0e38f;
        cpos += (lv == 1);
        cneg += (((unsigned)(i - js) < (unsigned)JS) && (lv == 0)) ? 1 : 0;
    }
    __syncthreads();

    // Hot loop: 32 float4 wave-uniform LDS broadcast reads, 48 VALU ops each.
    float acc[4] = {0.f, 0.f, 0.f, 0.f};
    const float4* d4 = (const float4*)(s_d + js);
#pragma unroll 4
    for (int c = 0; c < JS / 4; ++c) {
        const float4 d = d4[c];
#pragma unroll
        for (int k = 0; k < 4; ++k) {
            const float m0 = fmaxf(d.x - p[k], 0.0f) + fmaxf(d.y - p[k], 0.0f);
            const float m1 = fmaxf(d.z - p[k], 0.0f) + fmaxf(d.w - p[k], 0.0f);
            acc[k] += m0 + m1;
        }
    }
    float local = (acc[0] + acc[1]) + (acc[2] + acc[3]);

    // Block reduction: wave shuffle, then LDS combine.
#pragma unroll
    for (int off = 32; off >= 1; off >>= 1) {
        local += __shfl_down(local, off, 64);
        cpos  += __shfl_down(cpos,  off, 64);
        cneg  += __shfl_down(cneg,  off, 64);
    }
    const int wave = t >> 6;
    if ((t & 63) == 0) { s_wsum[wave] = local; s_wpos[wave] = cpos; s_wneg[wave] = cneg; }
    __syncthreads();
    if (t == 0) {
        float rs = 0.f; int rp = 0, rn = 0;
#pragma unroll
        for (int w = 0; w < 4; ++w) { rs += s_wsum[w]; rp += s_wpos[w]; rn += s_wneg[w]; }
        partial_sum[b * SPLIT + s] = rs;
        partial_neg[b * SPLIT + s] = rn;
        if (s == 0) pos_count[b] = rp;   // full-row pos count (block covers all i)
    }
}

__global__ __launch_bounds__(128) void prl_finalize(
    const float* __restrict__ partial_sum,
    const int*   __restrict__ partial_neg,
    const int*   __restrict__ pos_count,
    float* __restrict__ out)
{
    __shared__ float     s_sum[2];
    __shared__ long long s_pairs[2];
    const int t = threadIdx.x; // one thread per row, 128 threads

    float sum = 0.f; int neg = 0;
#pragma unroll
    for (int s = 0; s < SPLIT; ++s) {
        sum += partial_sum[t * SPLIT + s];
        neg += partial_neg[t * SPLIT + s];
    }
    long long pr = (long long)pos_count[t] * (long long)neg;

#pragma unroll
    for (int off = 32; off >= 1; off >>= 1) {
        sum += __shfl_down(sum, off, 64);
        pr  += __shfl_down(pr,  off, 64);
    }
    const int wave = t >> 6;
    if ((t & 63) == 0) { s_sum[wave] = sum; s_pairs[wave] = pr; }
    __syncthreads();
    if (t == 0) {
        const float     total = s_sum[0] + s_sum[1];
        const long long pairs = s_pairs[0] + s_pairs[1];
        out[0] = (pairs > 0) ? (total / fmaxf((float)pairs, 1.0f)) : total;
    }
}

extern "C" void kernel_launch(void* const* d_in, const int* in_sizes, int n_in,
                              void* d_out, int out_size, void* d_ws, size_t ws_size,
                              hipStream_t stream) {
    const float* y_pred = (const float*)d_in[0];
    const int*   y_true = (const int*)d_in[1];
    float* out = (float*)d_out;

    // Workspace: float partial_sum[B*SPLIT]; int partial_neg[B*SPLIT]; int pos_count[B]
    float* partial_sum = (float*)d_ws;
    int*   partial_neg = (int*)(partial_sum + PRL_B * SPLIT);
    int*   pos_count   = partial_neg + PRL_B * SPLIT;

    dim3 grid(SPLIT, PRL_B);
    prl_partial<<<grid, 256, 0, stream>>>(y_pred, y_true, partial_sum, partial_neg, pos_count);
    prl_finalize<<<1, PRL_B, 0, stream>>>(partial_sum, partial_neg, pos_count, out);
}